// Round 5
// baseline (147.262 us; speedup 1.0000x reference)
//
#include <hip/hip_runtime.h>
#include <hip/hip_bf16.h>
#include <math.h>

#define HF 32
#define WF 88
#define NCAM 6
#define CC 128
#define ZD 128
#define YD 8
#define XD 128

using f32x4  = __attribute__((ext_vector_type(4))) float;
using bf16x8 = __attribute__((ext_vector_type(8))) short;

// ---- workspace layout (bytes) ----
#define OFF_P    0ull
#define OFF_W    512ull                        // Wp: 9*131072*2 = 2359296
#define OFF_CAMT (OFF_W + 2359296ull)          // camT(bf16): 4325376 used of 8650752 slot (reused as conv1 after k2)
#define OFF_F    (OFF_CAMT + 8650752ull)       // Fpack: 130*130*1024*2 = 34611200
#define OFF_CONV (OFF_F + 34611200ull)         // conv partial 0: 128*16384*4 = 8388608
#define OFF_VB   (OFF_CONV + 8388608ull)       // validity bitmap: 128 z * 4 u32 = 2048

// ============ K0: camera matrices (+ zero the validity bitmap) ============
__global__ __launch_bounds__(64) void k0_mats(const float* __restrict__ cam2ego,
                                              const float* __restrict__ intr,
                                              float* __restrict__ P,
                                              unsigned* __restrict__ VB) {
  for (int i = threadIdx.x; i < 512; i += 64) VB[i] = 0u;
  int s = threadIdx.x;
  if (s >= NCAM) return;
  const float* M0 = cam2ego;
  const float* Ms = cam2ego + s * 16;
  float Rb[9], tb[3];
  for (int i = 0; i < 3; i++)
    for (int j = 0; j < 3; j++) {
      float v = 0.f;
      for (int k = 0; k < 3; k++) v += Ms[k * 4 + i] * M0[k * 4 + j];
      Rb[i * 3 + j] = v;
    }
  for (int i = 0; i < 3; i++) {
    float v = 0.f;
    for (int k = 0; k < 3; k++) v += Ms[k * 4 + i] * (M0[k * 4 + 3] - Ms[k * 4 + 3]);
    tb[i] = v;
  }
  const float* Ks = intr + s * 16;
  const float sx = (float)WF / 704.0f * 0.44f;
  const float sy = (float)HF / 256.0f * 0.284f;
  const float fx = Ks[0] * sx, fy = Ks[5] * sy;
  const float cx = Ks[2] * sx, cy = Ks[6] * sy;
  float* p = P + s * 12;
  for (int j = 0; j < 3; j++) p[j]     = fx * Rb[j]     + cx * Rb[6 + j];
  p[3]  = fx * tb[0] + cx * tb[2];
  for (int j = 0; j < 3; j++) p[4 + j] = fy * Rb[3 + j] + cy * Rb[6 + j];
  p[7]  = fy * tb[1] + cy * tb[2];
  for (int j = 0; j < 3; j++) p[8 + j] = Rb[6 + j];
  p[11] = tb[2];
}

// ============ K1: cam_feat (S,C,H,W) f32 -> camT (S,H,W,C) bf16 ============
__global__ __launch_bounds__(128) void k1_transpose(const float* __restrict__ feat,
                                                    __hip_bfloat16* __restrict__ camT) {
  const int b = blockIdx.x;
  const int wq = b & 3;
  const int sh = b >> 2;
  const int c = threadIdx.x;
  const float* src = feat + ((size_t)(sh / HF) * CC + c) * (HF * WF) + (sh % HF) * WF + wq * 22;
  __hip_bfloat16* dst = camT + ((size_t)sh * WF + wq * 22) * CC + c;
  for (int w = 0; w < 22; w++) dst[w * CC] = __float2bfloat16(src[w]);
}

// ============ K1b: conv_w (co,ci,3,3) f32 -> Wp[d][co*1024+ci] bf16 ============
__global__ __launch_bounds__(256) void k1b_packw(const float* __restrict__ w,
                                                 __hip_bfloat16* __restrict__ wp) {
  const int t = blockIdx.x * 256 + threadIdx.x;
  float v[9];
  #pragma unroll
  for (int d = 0; d < 9; d++) v[d] = w[(size_t)t * 9 + d];
  #pragma unroll
  for (int d = 0; d < 9; d++) wp[(size_t)d * 131072 + t] = __float2bfloat16(v[d]);
}

// ============ K2: project + bilinear + mask-average -> Fpack (halo-padded) ====
// v4: early-out for cells outside all camera frusta (~65% of BEV) + publish
// per-cell validity bitmap VB for k3's sparsity skip.
struct Rec { int off[4]; float w[4]; };

__global__ __launch_bounds__(256) void k2_sample(const __hip_bfloat16* __restrict__ camT,
                                                 const float* __restrict__ P,
                                                 __hip_bfloat16* __restrict__ F,
                                                 unsigned* __restrict__ VB) {
  const int bz = blockIdx.x / 130;
  const int bx = blockIdx.x % 130;
  const int t = threadIdx.x;
  const int zi = bz - 1, xi = bx - 1;
  const int c = (t & 63) << 1;      // channel pair base 0,2,..,126
  const int yq = t >> 6;            // y quarter: handles y = yq*2, yq*2+1
  __hip_bfloat16* Fb = F + (size_t)blockIdx.x * 1024;
  if (zi < 0 || zi >= ZD || xi < 0 || xi >= XD) {
    *reinterpret_cast<unsigned*>(Fb + c * 8 + yq * 2) = 0u;
    *reinterpret_cast<unsigned*>(Fb + (c + 1) * 8 + yq * 2) = 0u;
    return;
  }
  __shared__ Rec recs[48];
  __shared__ int anyv;
  bool v = false;
  if (t < 48) {
    const int y = t / 6, s = t - y * 6;
    const float* pp = P + s * 12;
    const float vx = 100.0f / 128.0f;
    const float xw = xi * vx - 50.0f + vx * 0.5f;
    const float zw = zi * vx - 50.0f + vx * 0.5f;
    const float yw = y * 1.25f - 4.0f + 0.625f;
    const float zc = pp[8] * xw + pp[9] * yw + pp[10] * zw + pp[11];
    const float xp = pp[0] * xw + pp[1] * yw + pp[2] * zw + pp[3];
    const float yp = pp[4] * xw + pp[5] * yw + pp[6] * zw + pp[7];
    const float dep = fmaxf(zc, 1e-4f);
    const float pxf = xp / dep, pyf = yp / dep;
    const bool valid = (pxf > -0.5f && pxf < (float)WF - 0.5f &&
                        pyf > -0.5f && pyf < (float)HF - 0.5f && zc > 0.0f);
    const float px = pxf * ((float)WF / (float)(WF - 1)) - 0.5f;
    const float py = pyf * ((float)HF / (float)(HF - 1)) - 0.5f;
    const float fx0 = floorf(px), fy0 = floorf(py);
    const float ddx = px - fx0, ddy = py - fy0;
    const int x0i = (int)fx0, y0i = (int)fy0;
    const float vf = valid ? 1.0f : 0.0f;
    float ww[4];
    ww[0] = (1.0f - ddx) * (1.0f - ddy) * vf;
    ww[1] = ddx * (1.0f - ddy) * vf;
    ww[2] = (1.0f - ddx) * ddy * vf;
    ww[3] = ddx * ddy * vf;
    const int cxs[4] = {x0i, x0i + 1, x0i, x0i + 1};
    const int cys[4] = {y0i, y0i, y0i + 1, y0i + 1};
    Rec r;
    #pragma unroll
    for (int k = 0; k < 4; k++) {
      const bool inb = ((unsigned)cxs[k] < WF) && ((unsigned)cys[k] < HF);
      const int xc = min(max(cxs[k], 0), WF - 1);
      const int yc = min(max(cys[k], 0), HF - 1);
      r.w[k] = inb ? ww[k] : 0.0f;
      r.off[k] = (s * (HF * WF) + yc * WF + xc) * CC;
    }
    recs[t] = r;
    v = (r.w[0] + r.w[1] + r.w[2] + r.w[3]) > 0.0f;
  }
  if (t < 64) {                       // wave 0 summarizes validity
    unsigned long long m = __ballot(v);
    if (t == 0) {
      anyv = (m != 0ull) ? 1 : 0;
      if (m) atomicOr(&VB[zi * 4 + (xi >> 5)], 1u << (xi & 31));
    }
  }
  __syncthreads();
  if (!anyv) {                        // outside all frusta: exact zeros
    *reinterpret_cast<unsigned*>(Fb + c * 8 + yq * 2) = 0u;
    *reinterpret_cast<unsigned*>(Fb + (c + 1) * 8 + yq * 2) = 0u;
    return;
  }

  float num[2][2] = {{0.f, 0.f}, {0.f, 0.f}};
  int cnt[2] = {0, 0};
  #pragma unroll
  for (int yi = 0; yi < 2; yi++) {
    const int y = yq * 2 + yi;
    for (int s = 0; s < NCAM; s++) {
      const Rec r = recs[y * 6 + s];
      if (r.w[0] == 0.f && r.w[1] == 0.f && r.w[2] == 0.f && r.w[3] == 0.f) continue;
      float v0 = 0.f, v1 = 0.f;
      #pragma unroll
      for (int k = 0; k < 4; k++) {
        const ushort2 uv = *reinterpret_cast<const ushort2*>(&camT[r.off[k] + c]);
        v0 += r.w[k] * __bfloat162float(*reinterpret_cast<const __hip_bfloat16*>(&uv.x));
        v1 += r.w[k] * __bfloat162float(*reinterpret_cast<const __hip_bfloat16*>(&uv.y));
      }
      num[yi][0] += v0;
      num[yi][1] += v1;
      cnt[yi]++;
    }
  }
  #pragma unroll
  for (int j = 0; j < 2; j++) {
    __hip_bfloat16 o[2];
    const float inv0 = 1.0f / (1e-6f + (float)cnt[0]);
    const float inv1 = 1.0f / (1e-6f + (float)cnt[1]);
    o[0] = __float2bfloat16(num[0][j] * inv0);
    o[1] = __float2bfloat16(num[1][j] * inv1);
    *reinterpret_cast<unsigned*>(Fb + (c + j) * 8 + yq * 2) =
        *reinterpret_cast<const unsigned*>(o);
  }
}

// ============ K3: implicit-GEMM 3x3 conv, bf16 MFMA, sparsity-skipped ============
// v6 = v5 (BK=128, ring-2, 36 steps) + per-16-row-group zero skip from VB:
// zero groups skip A-staging (wave-uniform: wave w stages exactly group w),
// a[m] ds_reads and MFMAs (acc stays exactly 0). Per-wave stage load count is
// constant (4 or 8) -> counted wait is vmcnt(8) or vmcnt(4) per wave.
__device__ __forceinline__ void load_lds16(const void* g, void* l) {
  __builtin_amdgcn_global_load_lds(
      (const __attribute__((address_space(1))) unsigned int*)g,
      (__attribute__((address_space(3))) unsigned int*)l, 16, 0, 0);
}

#define K3_NT 36   // 36 steps x BK=128 = 9 taps * 8 x 64-ci sub-chunks (ci-half)

__global__ __launch_bounds__(512) void k3_gemm(const __hip_bfloat16* __restrict__ F,
                                               const __hip_bfloat16* __restrict__ Wp,
                                               const unsigned* __restrict__ VB,
                                               float* __restrict__ out0,
                                               float* __restrict__ out1) {
  // XCD-aware swizzle: 32 consecutive logical blocks per XCD (256 = 8*32).
  const int orig = (blockIdx.x & 7) * 32 + (blockIdx.x >> 3);
  const int z = orig & 127;
  const int h = orig >> 7;          // ci-half: 0 -> ci 0..511, 1 -> 512..1023
  const int ciH = h << 9;
  const int tid = threadIdx.x;
  const int w = tid >> 6;           // wave 0..7
  const int l = tid & 63;
  const int wm = w >> 2;            // 0..1  (64 x-rows)
  const int wn = w & 3;             // 0..3  (32 co)
  // ring-2, per buf: [A_k0 16K][B_k0 16K][A_k1 16K][B_k1 16K] = 64KB
  __shared__ __hip_bfloat16 lds[65536];

  // ---- group nonzero mask: 8 groups of 16 x-rows; window [16G-1, 16G+16]
  // over VB[z-1]|VB[z]|VB[z+1] covers the 3x3 tap halo exactly. ----
  unsigned C[4] = {0u, 0u, 0u, 0u};
  #pragma unroll
  for (int dz = -1; dz <= 1; ++dz) {
    const int zz = z + dz;
    if (zz < 0 || zz >= ZD) continue;
    C[0] |= VB[zz * 4 + 0]; C[1] |= VB[zz * 4 + 1];
    C[2] |= VB[zz * 4 + 2]; C[3] |= VB[zz * 4 + 3];
  }
  unsigned gmask = 0;
  #pragma unroll
  for (int G = 0; G < 8; ++G) {
    const int lo = (G * 16 - 1 < 0) ? 0 : G * 16 - 1;
    const int hi = (G * 16 + 16 > 127) ? 127 : G * 16 + 16;
    unsigned nz = 0;
    for (int b = lo; b <= hi; ++b) nz |= (C[b >> 5] >> (b & 31)) & 1u;
    gmask |= nz << G;
  }
  const bool aw = (gmask >> w) & 1;   // this wave's staged A-group nonzero?

  f32x4 acc[4][2];
  #pragma unroll
  for (int m = 0; m < 4; m++)
    #pragma unroll
    for (int n = 0; n < 2; n++)
      acc[m][n] = (f32x4){0.f, 0.f, 0.f, 0.f};

  // one 64-ci sub-stage; sub = global 64-ci chunk index 0..71
  auto stage_sub = [&](int sub) {
    const int base = ((sub >> 1) & 1) * 32768 + (sub & 1) * 16384;
    const int d = sub >> 3;                   // tap 0..8
    const int dz = d / 3, dx = d - dz * 3;
    const int ci0 = ciH + ((sub & 7) << 6);
    const int zbase = (z + dz) * 130 + dx;
    // A: 128 x-rows x 64 ci; wave w covers rows 16w..16w+15 = group w.
    if (aw) {
      #pragma unroll
      for (int i = 0; i < 2; i++) {
        const int n = w * 128 + i * 64 + l;
        const int row = n >> 3;
        const int q = (n & 7) ^ (row & 7);
        const __hip_bfloat16* src = F + ((size_t)(zbase + row) << 10) + ci0 + (q << 3);
        load_lds16(src, &lds[base + (w * 128 + i * 64) * 8]);
      }
    }
    // B: 128 co x 64 ci, same swizzle (always needed)
    #pragma unroll
    for (int i = 0; i < 2; i++) {
      const int n = w * 128 + i * 64 + l;
      const int co = n >> 3;
      const int q = (n & 7) ^ (co & 7);
      const __hip_bfloat16* src = Wp + ((size_t)d << 17) + ((size_t)co << 10) + ci0 + (q << 3);
      load_lds16(src, &lds[base + 8192 + (w * 128 + i * 64) * 8]);
    }
  };
  auto stage = [&](int T) { stage_sub(2 * T); stage_sub(2 * T + 1); };

  auto compute_sub = [&](int base) {
    const int r16 = l & 15;
    const int hi = l >> 4;
    #pragma unroll
    for (int kk = 0; kk < 2; kk++) {
      const int c = kk * 4 + hi;              // 16B ci-chunk 0..7
      bf16x8 a[4], b[2];
      #pragma unroll
      for (int m = 0; m < 4; m++) {
        if ((gmask >> (wm * 4 + m)) & 1) {
          const int r = wm * 64 + m * 16 + r16;
          const int slot = c ^ (r & 7);
          a[m] = *reinterpret_cast<const bf16x8*>(&lds[base + r * 64 + slot * 8]);
        }
      }
      #pragma unroll
      for (int n = 0; n < 2; n++) {
        const int co = wn * 32 + n * 16 + r16;
        const int slot = c ^ (co & 7);
        b[n] = *reinterpret_cast<const bf16x8*>(&lds[base + 8192 + co * 64 + slot * 8]);
      }
      __builtin_amdgcn_s_setprio(1);
      #pragma unroll
      for (int m = 0; m < 4; m++) {
        if ((gmask >> (wm * 4 + m)) & 1) {
          #pragma unroll
          for (int n = 0; n < 2; n++)
            acc[m][n] = __builtin_amdgcn_mfma_f32_16x16x32_bf16(a[m], b[n], acc[m][n], 0, 0, 0);
        }
      }
      __builtin_amdgcn_s_setprio(0);
    }
  };
  auto compute = [&](int T) {
    const int b0 = (T & 1) * 32768;
    compute_sub(b0);
    compute_sub(b0 + 16384);
  };

  if (gmask != 0) {
    // prologue: both buffers issued; wait for buf0 (one stage in flight)
    stage(0); stage(1);
    if (aw) asm volatile("s_waitcnt vmcnt(8)" ::: "memory");
    else    asm volatile("s_waitcnt vmcnt(4)" ::: "memory");
    __builtin_amdgcn_s_barrier();

    for (int t = 0; t < K3_NT; ++t) {
      compute(t);
      __builtin_amdgcn_s_barrier();          // all waves done reading buf[t&1]
      if (t + 2 < K3_NT) {
        stage(t + 2);                        // refill buf[t&1]
        if (aw) asm volatile("s_waitcnt vmcnt(8)" ::: "memory");  // stage(t+1) done
        else    asm volatile("s_waitcnt vmcnt(4)" ::: "memory");
      } else {
        asm volatile("s_waitcnt vmcnt(0)" ::: "memory");          // drain tail
      }
      __builtin_amdgcn_s_barrier();          // buf[(t+1)&1] ready
    }
  }

  // epilogue: plain vector stores (zero groups store exact zeros)
  float* outP = h ? out1 : out0;
  const int r16 = l & 15;
  const int hi = l >> 4;
  #pragma unroll
  for (int m = 0; m < 4; m++) {
    const int xr = wm * 64 + m * 16 + hi * 4;
    #pragma unroll
    for (int n = 0; n < 2; n++) {
      const int co = wn * 32 + n * 16 + r16;
      *reinterpret_cast<f32x4*>(&outP[((size_t)co << 14) + (z << 7) + xr]) = acc[m][n];
    }
  }
}

// ============ K4: fused split-K reduce + per-channel LN + exact GELU ============
__device__ __forceinline__ float gelu_exact(float x) {
  return 0.5f * x * (1.0f + erff(x * 0.70710678118654752440f));
}

__global__ __launch_bounds__(256) void k4_ln(const float* __restrict__ c0,
                                             const float* __restrict__ c1,
                                             float* __restrict__ outp) {
  const int co = blockIdx.x;
  const float4* p0 = reinterpret_cast<const float4*>(c0 + ((size_t)co << 14));
  const float4* p1 = reinterpret_cast<const float4*>(c1 + ((size_t)co << 14));
  float4 v[16];
  float s = 0.f, s2 = 0.f;
  #pragma unroll
  for (int i = 0; i < 16; i++) {
    float4 a = p0[threadIdx.x + (i << 8)];
    float4 b = p1[threadIdx.x + (i << 8)];
    float4 t;
    t.x = a.x + b.x; t.y = a.y + b.y; t.z = a.z + b.z; t.w = a.w + b.w;
    v[i] = t;
    s  += t.x + t.y + t.z + t.w;
    s2 += t.x * t.x + t.y * t.y + t.z * t.z + t.w * t.w;
  }
  #pragma unroll
  for (int off = 32; off > 0; off >>= 1) {
    s  += __shfl_down(s, off);
    s2 += __shfl_down(s2, off);
  }
  __shared__ float red[8];
  __shared__ float mb[2];
  const int wv = threadIdx.x >> 6, ln = threadIdx.x & 63;
  if (ln == 0) { red[wv] = s; red[wv + 4] = s2; }
  __syncthreads();
  if (threadIdx.x == 0) {
    float S  = red[0] + red[1] + red[2] + red[3];
    float S2 = red[4] + red[5] + red[6] + red[7];
    float mu = S * (1.0f / 16384.0f);
    float var = S2 * (1.0f / 16384.0f) - mu * mu;
    mb[0] = mu;
    mb[1] = 1.0f / sqrtf(var + 1e-5f);
  }
  __syncthreads();
  const float mu = mb[0], inv = mb[1];
  float4* op = reinterpret_cast<float4*>(outp + ((size_t)co << 14));
  #pragma unroll
  for (int i = 0; i < 16; i++) {
    float4 t = v[i];
    float4 r;
    r.x = gelu_exact((t.x - mu) * inv);
    r.y = gelu_exact((t.y - mu) * inv);
    r.z = gelu_exact((t.z - mu) * inv);
    r.w = gelu_exact((t.w - mu) * inv);
    op[threadIdx.x + (i << 8)] = r;
  }
}

extern "C" void kernel_launch(void* const* d_in, const int* in_sizes, int n_in,
                              void* d_out, int out_size, void* d_ws, size_t ws_size,
                              hipStream_t stream) {
  const float* cam_feat = (const float*)d_in[0];
  const float* cam2ego  = (const float*)d_in[1];
  const float* intr     = (const float*)d_in[2];
  const float* conv_w   = (const float*)d_in[3];
  float* out = (float*)d_out;
  char* ws = (char*)d_ws;

  float*          P     = (float*)(ws + OFF_P);
  __hip_bfloat16* Wp    = (__hip_bfloat16*)(ws + OFF_W);
  __hip_bfloat16* camT  = (__hip_bfloat16*)(ws + OFF_CAMT);
  __hip_bfloat16* F     = (__hip_bfloat16*)(ws + OFF_F);
  float*          conv0 = (float*)(ws + OFF_CONV);
  float*          conv1 = (float*)(ws + OFF_CAMT);  // camT slot is dead after k2
  unsigned*       VB    = (unsigned*)(ws + OFF_VB);

  hipLaunchKernelGGL(k0_mats, dim3(1), dim3(64), 0, stream, cam2ego, intr, P, VB);
  hipLaunchKernelGGL(k1_transpose, dim3(NCAM * HF * 4), dim3(128), 0, stream, cam_feat, camT);
  hipLaunchKernelGGL(k1b_packw, dim3(512), dim3(256), 0, stream, conv_w, Wp);
  hipLaunchKernelGGL(k2_sample, dim3(130 * 130), dim3(256), 0, stream, camT, P, F, VB);
  hipLaunchKernelGGL(k3_gemm, dim3(256), dim3(512), 0, stream, F, Wp, VB, conv0, conv1);
  hipLaunchKernelGGL(k4_ln, dim3(128), dim3(256), 0, stream, conv0, conv1, out);
}

// Round 6
// 112.765 us; speedup vs baseline: 1.3059x; 1.3059x over previous
//
#include <hip/hip_runtime.h>
#include <hip/hip_bf16.h>
#include <math.h>

#define HF 32
#define WF 88
#define NCAM 6
#define CC 128
#define ZD 128
#define YD 8
#define XD 128

using f32x4  = __attribute__((ext_vector_type(4))) float;
using bf16x8 = __attribute__((ext_vector_type(8))) short;

// ---- workspace layout (bytes) ----
#define OFF_P    0ull
#define OFF_W    512ull                        // Wp: 9*131072*2 = 2359296
#define OFF_CAMT (OFF_W + 2359296ull)          // camT(bf16): 4325376 used of 8650752 slot (reused as conv1 after k2)
#define OFF_F    (OFF_CAMT + 8650752ull)       // Fpack: 130*130*1024*2 = 34611200
#define OFF_CONV (OFF_F + 34611200ull)         // conv partial 0: 128*16384*4 = 8388608

// ============ K0: camera matrices ============
__global__ __launch_bounds__(64) void k0_mats(const float* __restrict__ cam2ego,
                                              const float* __restrict__ intr,
                                              float* __restrict__ P) {
  int s = threadIdx.x;
  if (s >= NCAM) return;
  const float* M0 = cam2ego;
  const float* Ms = cam2ego + s * 16;
  float Rb[9], tb[3];
  for (int i = 0; i < 3; i++)
    for (int j = 0; j < 3; j++) {
      float v = 0.f;
      for (int k = 0; k < 3; k++) v += Ms[k * 4 + i] * M0[k * 4 + j];
      Rb[i * 3 + j] = v;
    }
  for (int i = 0; i < 3; i++) {
    float v = 0.f;
    for (int k = 0; k < 3; k++) v += Ms[k * 4 + i] * (M0[k * 4 + 3] - Ms[k * 4 + 3]);
    tb[i] = v;
  }
  const float* Ks = intr + s * 16;
  const float sx = (float)WF / 704.0f * 0.44f;
  const float sy = (float)HF / 256.0f * 0.284f;
  const float fx = Ks[0] * sx, fy = Ks[5] * sy;
  const float cx = Ks[2] * sx, cy = Ks[6] * sy;
  float* p = P + s * 12;
  for (int j = 0; j < 3; j++) p[j]     = fx * Rb[j]     + cx * Rb[6 + j];
  p[3]  = fx * tb[0] + cx * tb[2];
  for (int j = 0; j < 3; j++) p[4 + j] = fy * Rb[3 + j] + cy * Rb[6 + j];
  p[7]  = fy * tb[1] + cy * tb[2];
  for (int j = 0; j < 3; j++) p[8 + j] = Rb[6 + j];
  p[11] = tb[2];
}

// ============ K1: cam_feat (S,C,H,W) f32 -> camT (S,H,W,C) bf16 ============
__global__ __launch_bounds__(128) void k1_transpose(const float* __restrict__ feat,
                                                    __hip_bfloat16* __restrict__ camT) {
  const int b = blockIdx.x;
  const int wq = b & 3;
  const int sh = b >> 2;
  const int c = threadIdx.x;
  const float* src = feat + ((size_t)(sh / HF) * CC + c) * (HF * WF) + (sh % HF) * WF + wq * 22;
  __hip_bfloat16* dst = camT + ((size_t)sh * WF + wq * 22) * CC + c;
  for (int w = 0; w < 22; w++) dst[w * CC] = __float2bfloat16(src[w]);
}

// ============ K1b: conv_w (co,ci,3,3) f32 -> Wp[d][co*1024+ci] bf16 ============
__global__ __launch_bounds__(256) void k1b_packw(const float* __restrict__ w,
                                                 __hip_bfloat16* __restrict__ wp) {
  const int t = blockIdx.x * 256 + threadIdx.x;
  float v[9];
  #pragma unroll
  for (int d = 0; d < 9; d++) v[d] = w[(size_t)t * 9 + d];
  #pragma unroll
  for (int d = 0; d < 9; d++) wp[(size_t)d * 131072 + t] = __float2bfloat16(v[d]);
}

// ============ K2: project + bilinear + mask-average -> Fpack (halo-padded) ====
// v5: block-uniform per-y camera bitmask (one ballot in wave 0) replaces the
// per-thread 12x Rec-load+zero-check scan; phase 2 iterates only valid recs
// via a uniform ctz loop. Removes ~70% of phase-2 LDS reads + compares.
struct Rec { int off[4]; float w[4]; };

__global__ __launch_bounds__(256) void k2_sample(const __hip_bfloat16* __restrict__ camT,
                                                 const float* __restrict__ P,
                                                 __hip_bfloat16* __restrict__ F) {
  const int bz = blockIdx.x / 130;
  const int bx = blockIdx.x % 130;
  const int t = threadIdx.x;
  const int zi = bz - 1, xi = bx - 1;
  const int c = (t & 63) << 1;      // channel pair base 0,2,..,126
  const int yq = t >> 6;            // y quarter: handles y = yq*2, yq*2+1
  __hip_bfloat16* Fb = F + (size_t)blockIdx.x * 1024;
  if (zi < 0 || zi >= ZD || xi < 0 || xi >= XD) {
    *reinterpret_cast<unsigned*>(Fb + c * 8 + yq * 2) = 0u;
    *reinterpret_cast<unsigned*>(Fb + (c + 1) * 8 + yq * 2) = 0u;
    return;
  }
  __shared__ Rec recs[48];
  __shared__ unsigned ymask[8];     // per-y bitmask of valid cameras
  bool vflag = false;
  if (t < 48) {
    const int y = t / 6, s = t - y * 6;
    const float* pp = P + s * 12;
    const float vx = 100.0f / 128.0f;
    const float xw = xi * vx - 50.0f + vx * 0.5f;
    const float zw = zi * vx - 50.0f + vx * 0.5f;
    const float yw = y * 1.25f - 4.0f + 0.625f;
    const float zc = pp[8] * xw + pp[9] * yw + pp[10] * zw + pp[11];
    const float xp = pp[0] * xw + pp[1] * yw + pp[2] * zw + pp[3];
    const float yp = pp[4] * xw + pp[5] * yw + pp[6] * zw + pp[7];
    const float dep = fmaxf(zc, 1e-4f);
    const float pxf = xp / dep, pyf = yp / dep;
    const bool valid = (pxf > -0.5f && pxf < (float)WF - 0.5f &&
                        pyf > -0.5f && pyf < (float)HF - 0.5f && zc > 0.0f);
    const float px = pxf * ((float)WF / (float)(WF - 1)) - 0.5f;
    const float py = pyf * ((float)HF / (float)(HF - 1)) - 0.5f;
    const float fx0 = floorf(px), fy0 = floorf(py);
    const float ddx = px - fx0, ddy = py - fy0;
    const int x0i = (int)fx0, y0i = (int)fy0;
    const float vf = valid ? 1.0f : 0.0f;
    float ww[4];
    ww[0] = (1.0f - ddx) * (1.0f - ddy) * vf;
    ww[1] = ddx * (1.0f - ddy) * vf;
    ww[2] = (1.0f - ddx) * ddy * vf;
    ww[3] = ddx * ddy * vf;
    const int cxs[4] = {x0i, x0i + 1, x0i, x0i + 1};
    const int cys[4] = {y0i, y0i, y0i + 1, y0i + 1};
    Rec r;
    float wsum = 0.f;
    #pragma unroll
    for (int k = 0; k < 4; k++) {
      const bool inb = ((unsigned)cxs[k] < WF) && ((unsigned)cys[k] < HF);
      const int xc = min(max(cxs[k], 0), WF - 1);
      const int yc = min(max(cys[k], 0), HF - 1);
      r.w[k] = inb ? ww[k] : 0.0f;
      r.off[k] = (s * (HF * WF) + yc * WF + xc) * CC;
      wsum += r.w[k];
    }
    recs[t] = r;
    vflag = wsum > 0.0f;            // non-negative weights: >0 <=> not all zero
  }
  if (t < 64) {                     // wave 0 summarizes validity (uniform exec)
    unsigned long long m = __ballot(vflag);
    if (t < 8) ymask[t] = (unsigned)((m >> (6 * t)) & 63ull);
  }
  __syncthreads();

  float num[2][2] = {{0.f, 0.f}, {0.f, 0.f}};
  int cnt[2] = {0, 0};
  #pragma unroll
  for (int yi = 0; yi < 2; yi++) {
    const int y = yq * 2 + yi;
    unsigned ms = ymask[y];         // block-uniform
    while (ms) {
      const int s = __builtin_ctz(ms);
      ms &= ms - 1;
      const Rec r = recs[y * 6 + s];
      float v0 = 0.f, v1 = 0.f;
      #pragma unroll
      for (int k = 0; k < 4; k++) {
        const ushort2 uv = *reinterpret_cast<const ushort2*>(&camT[r.off[k] + c]);
        v0 += r.w[k] * __bfloat162float(*reinterpret_cast<const __hip_bfloat16*>(&uv.x));
        v1 += r.w[k] * __bfloat162float(*reinterpret_cast<const __hip_bfloat16*>(&uv.y));
      }
      num[yi][0] += v0;
      num[yi][1] += v1;
      cnt[yi]++;
    }
  }
  #pragma unroll
  for (int j = 0; j < 2; j++) {
    __hip_bfloat16 o[2];
    const float inv0 = 1.0f / (1e-6f + (float)cnt[0]);
    const float inv1 = 1.0f / (1e-6f + (float)cnt[1]);
    o[0] = __float2bfloat16(num[0][j] * inv0);
    o[1] = __float2bfloat16(num[1][j] * inv1);
    *reinterpret_cast<unsigned*>(Fb + (c + j) * 8 + yq * 2) =
        *reinterpret_cast<const unsigned*>(o);
  }
}

// ============ K3: implicit-GEMM 3x3 conv, bf16 MFMA ============
// REVERTED to v3 (best measured: 54.6 us). 128x128 tile, BK=64, split-K=2
// across blocks (ci-halves) AND kk-split inside the block: waves 0-3 take ci
// sub-chunks 0..3 of each staged 64-ci tile, waves 4-7 take 4..7. Per-wave
// output 64x64 (acc 4x4). One 64KB LDS reduction merges kk pairs at the end.
// Ring-4 staging, counted vmcnt(8), no atomics.
__device__ __forceinline__ void load_lds16(const void* g, void* l) {
  __builtin_amdgcn_global_load_lds(
      (const __attribute__((address_space(1))) unsigned int*)g,
      (__attribute__((address_space(3))) unsigned int*)l, 16, 0, 0);
}

#define K3_NT 72   // 9 taps * 8 ci-chunks (ci-half of 512, BK=64)

__global__ __launch_bounds__(512) void k3_gemm(const __hip_bfloat16* __restrict__ F,
                                               const __hip_bfloat16* __restrict__ Wp,
                                               float* __restrict__ out0,
                                               float* __restrict__ out1) {
  // XCD-aware swizzle: 32 consecutive logical blocks per XCD (256 = 8*32).
  const int orig = (blockIdx.x & 7) * 32 + (blockIdx.x >> 3);
  const int z = orig & 127;
  const int h = orig >> 7;          // ci-half: 0 -> ci 0..511, 1 -> 512..1023
  const int ciH = h << 9;
  const int tid = threadIdx.x;
  const int w = tid >> 6;           // wave 0..7
  const int l = tid & 63;
  const int kk = w >> 2;            // in-block K-group (ci sub-chunks)
  const int wq = w & 3;
  const int wm = wq >> 1;           // 0..1  (64 x-rows)
  const int wn = wq & 1;            // 0..1  (64 co)
  __shared__ __hip_bfloat16 lds[4][16384];  // ring: A[128][64] + B[128][64] per stage (32KB)

  f32x4 acc[4][4];
  #pragma unroll
  for (int m = 0; m < 4; m++)
    #pragma unroll
    for (int n = 0; n < 4; n++)
      acc[m][n] = (f32x4){0.f, 0.f, 0.f, 0.f};

  auto stage = [&](int kt) {
    const int buf = kt & 3;
    const int d = kt >> 3;                    // tap 0..8
    const int dz = d / 3, dx = d - dz * 3;
    const int ci0 = ciH + ((kt & 7) << 6);
    const int zbase = (z + dz) * 130 + dx;
    // A: 128 x-rows x 64 ci = 1024 x 16B chunks; chunk n -> (row=n>>3, slot=n&7)
    // content at (row,slot) = ci-chunk (slot ^ (row&7))  [XOR swizzle]
    #pragma unroll
    for (int i = 0; i < 2; i++) {
      const int n = w * 128 + i * 64 + l;
      const int row = n >> 3;
      const int q = (n & 7) ^ (row & 7);
      const __hip_bfloat16* src = F + ((size_t)(zbase + row) << 10) + ci0 + (q << 3);
      load_lds16(src, &lds[buf][(w * 128 + i * 64) * 8]);
    }
    // B: 128 co x 64 ci, same swizzle
    #pragma unroll
    for (int i = 0; i < 2; i++) {
      const int n = w * 128 + i * 64 + l;
      const int co = n >> 3;
      const int q = (n & 7) ^ (co & 7);
      const __hip_bfloat16* src = Wp + ((size_t)d << 17) + ((size_t)co << 10) + ci0 + (q << 3);
      load_lds16(src, &lds[buf][8192 + (w * 128 + i * 64) * 8]);
    }
  };

  auto compute = [&](int kt) {
    const int buf = kt & 3;
    const int r16 = l & 15;
    const int hi = l >> 4;
    const int c = kk * 4 + hi;                // 16B ci-chunk 0..7 (kk-split)
    bf16x8 a[4], b[4];
    #pragma unroll
    for (int m = 0; m < 4; m++) {
      const int r = wm * 64 + m * 16 + r16;
      const int slot = c ^ (r & 7);
      a[m] = *reinterpret_cast<const bf16x8*>(&lds[buf][r * 64 + slot * 8]);
    }
    #pragma unroll
    for (int n = 0; n < 4; n++) {
      const int co = wn * 64 + n * 16 + r16;
      const int slot = c ^ (co & 7);
      b[n] = *reinterpret_cast<const bf16x8*>(&lds[buf][8192 + co * 64 + slot * 8]);
    }
    #pragma unroll
    for (int m = 0; m < 4; m++)
      #pragma unroll
      for (int n = 0; n < 4; n++)
        acc[m][n] = __builtin_amdgcn_mfma_f32_16x16x32_bf16(a[m], b[n], acc[m][n], 0, 0, 0);
  };

  // prologue: 3 stages in flight (12 outstanding loads/wave)
  stage(0); stage(1); stage(2);

  // main loop: wait only for oldest stage (vmcnt 8 = 2 stages still in flight)
  for (int t = 0; t < K3_NT - 2; ++t) {
    asm volatile("s_waitcnt vmcnt(8)" ::: "memory");
    __builtin_amdgcn_s_barrier();
    if (t + 3 < K3_NT) stage(t + 3);
    compute(t);
  }
  asm volatile("s_waitcnt vmcnt(4)" ::: "memory");
  __builtin_amdgcn_s_barrier();
  compute(K3_NT - 2);
  asm volatile("s_waitcnt vmcnt(0)" ::: "memory");
  __builtin_amdgcn_s_barrier();
  compute(K3_NT - 1);

  // ---- merge kk pairs: waves 4-7 dump acc to LDS, waves 0-3 add + store ----
  float* red = reinterpret_cast<float*>(&lds[0][0]);   // 64 KB scratch (bufs 0-1)
  if (kk == 1) {
    float* dst = red + wq * 4096;
    #pragma unroll
    for (int m = 0; m < 4; m++)
      #pragma unroll
      for (int n = 0; n < 4; n++)
        *reinterpret_cast<f32x4*>(&dst[(m * 4 + n) * 256 + l * 4]) = acc[m][n];
  }
  __syncthreads();
  if (kk == 0) {
    const float* srcr = red + wq * 4096;
    float* outP = h ? out1 : out0;
    const int r16 = l & 15;
    const int hi = l >> 4;
    #pragma unroll
    for (int m = 0; m < 4; m++) {
      const int xr = wm * 64 + m * 16 + hi * 4;
      #pragma unroll
      for (int n = 0; n < 4; n++) {
        f32x4 o = *reinterpret_cast<const f32x4*>(&srcr[(m * 4 + n) * 256 + l * 4]);
        f32x4 r = acc[m][n] + o;
        const int co = wn * 64 + n * 16 + r16;
        *reinterpret_cast<f32x4*>(&outP[((size_t)co << 14) + (z << 7) + xr]) = r;
      }
    }
  }
}

// ============ K4: fused split-K reduce + per-channel LN + exact GELU ============
__device__ __forceinline__ float gelu_exact(float x) {
  return 0.5f * x * (1.0f + erff(x * 0.70710678118654752440f));
}

__global__ __launch_bounds__(256) void k4_ln(const float* __restrict__ c0,
                                             const float* __restrict__ c1,
                                             float* __restrict__ outp) {
  const int co = blockIdx.x;
  const float4* p0 = reinterpret_cast<const float4*>(c0 + ((size_t)co << 14));
  const float4* p1 = reinterpret_cast<const float4*>(c1 + ((size_t)co << 14));
  float4 v[16];
  float s = 0.f, s2 = 0.f;
  #pragma unroll
  for (int i = 0; i < 16; i++) {
    float4 a = p0[threadIdx.x + (i << 8)];
    float4 b = p1[threadIdx.x + (i << 8)];
    float4 t;
    t.x = a.x + b.x; t.y = a.y + b.y; t.z = a.z + b.z; t.w = a.w + b.w;
    v[i] = t;
    s  += t.x + t.y + t.z + t.w;
    s2 += t.x * t.x + t.y * t.y + t.z * t.z + t.w * t.w;
  }
  #pragma unroll
  for (int off = 32; off > 0; off >>= 1) {
    s  += __shfl_down(s, off);
    s2 += __shfl_down(s2, off);
  }
  __shared__ float red[8];
  __shared__ float mb[2];
  const int wv = threadIdx.x >> 6, ln = threadIdx.x & 63;
  if (ln == 0) { red[wv] = s; red[wv + 4] = s2; }
  __syncthreads();
  if (threadIdx.x == 0) {
    float S  = red[0] + red[1] + red[2] + red[3];
    float S2 = red[4] + red[5] + red[6] + red[7];
    float mu = S * (1.0f / 16384.0f);
    float var = S2 * (1.0f / 16384.0f) - mu * mu;
    mb[0] = mu;
    mb[1] = 1.0f / sqrtf(var + 1e-5f);
  }
  __syncthreads();
  const float mu = mb[0], inv = mb[1];
  float4* op = reinterpret_cast<float4*>(outp + ((size_t)co << 14));
  #pragma unroll
  for (int i = 0; i < 16; i++) {
    float4 t = v[i];
    float4 r;
    r.x = gelu_exact((t.x - mu) * inv);
    r.y = gelu_exact((t.y - mu) * inv);
    r.z = gelu_exact((t.z - mu) * inv);
    r.w = gelu_exact((t.w - mu) * inv);
    op[threadIdx.x + (i << 8)] = r;
  }
}

extern "C" void kernel_launch(void* const* d_in, const int* in_sizes, int n_in,
                              void* d_out, int out_size, void* d_ws, size_t ws_size,
                              hipStream_t stream) {
  const float* cam_feat = (const float*)d_in[0];
  const float* cam2ego  = (const float*)d_in[1];
  const float* intr     = (const float*)d_in[2];
  const float* conv_w   = (const float*)d_in[3];
  float* out = (float*)d_out;
  char* ws = (char*)d_ws;

  float*          P     = (float*)(ws + OFF_P);
  __hip_bfloat16* Wp    = (__hip_bfloat16*)(ws + OFF_W);
  __hip_bfloat16* camT  = (__hip_bfloat16*)(ws + OFF_CAMT);
  __hip_bfloat16* F     = (__hip_bfloat16*)(ws + OFF_F);
  float*          conv0 = (float*)(ws + OFF_CONV);
  float*          conv1 = (float*)(ws + OFF_CAMT);  // camT slot is dead after k2

  hipLaunchKernelGGL(k0_mats, dim3(1), dim3(64), 0, stream, cam2ego, intr, P);
  hipLaunchKernelGGL(k1_transpose, dim3(NCAM * HF * 4), dim3(128), 0, stream, cam_feat, camT);
  hipLaunchKernelGGL(k1b_packw, dim3(512), dim3(256), 0, stream, conv_w, Wp);
  hipLaunchKernelGGL(k2_sample, dim3(130 * 130), dim3(256), 0, stream, camT, P, F);
  hipLaunchKernelGGL(k3_gemm, dim3(256), dim3(512), 0, stream, F, Wp, conv0, conv1);
  hipLaunchKernelGGL(k4_ln, dim3(128), dim3(256), 0, stream, conv0, conv1, out);
}

// Round 7
// 109.671 us; speedup vs baseline: 1.3428x; 1.0282x over previous
//
#include <hip/hip_runtime.h>
#include <hip/hip_bf16.h>
#include <math.h>

#define HF 32
#define WF 88
#define NCAM 6
#define CC 128
#define ZD 128
#define YD 8
#define XD 128

using f32x4  = __attribute__((ext_vector_type(4))) float;
using bf16x8 = __attribute__((ext_vector_type(8))) short;

// ---- workspace layout (bytes) ----
#define OFF_P    0ull
#define OFF_W    512ull                        // Wp: 9*131072*2 = 2359296
#define OFF_CAMT (OFF_W + 2359296ull)          // camT(bf16): 4325376 used of 8650752 slot (reused as conv1 after k2)
#define OFF_F    (OFF_CAMT + 8650752ull)       // Fpack: 130*130*1024*2 = 34611200
#define OFF_CONV (OFF_F + 34611200ull)         // conv partial 0: 128*16384*4 = 8388608

// ============ K0: camera matrices ============
__global__ __launch_bounds__(64) void k0_mats(const float* __restrict__ cam2ego,
                                              const float* __restrict__ intr,
                                              float* __restrict__ P) {
  int s = threadIdx.x;
  if (s >= NCAM) return;
  const float* M0 = cam2ego;
  const float* Ms = cam2ego + s * 16;
  float Rb[9], tb[3];
  for (int i = 0; i < 3; i++)
    for (int j = 0; j < 3; j++) {
      float v = 0.f;
      for (int k = 0; k < 3; k++) v += Ms[k * 4 + i] * M0[k * 4 + j];
      Rb[i * 3 + j] = v;
    }
  for (int i = 0; i < 3; i++) {
    float v = 0.f;
    for (int k = 0; k < 3; k++) v += Ms[k * 4 + i] * (M0[k * 4 + 3] - Ms[k * 4 + 3]);
    tb[i] = v;
  }
  const float* Ks = intr + s * 16;
  const float sx = (float)WF / 704.0f * 0.44f;
  const float sy = (float)HF / 256.0f * 0.284f;
  const float fx = Ks[0] * sx, fy = Ks[5] * sy;
  const float cx = Ks[2] * sx, cy = Ks[6] * sy;
  float* p = P + s * 12;
  for (int j = 0; j < 3; j++) p[j]     = fx * Rb[j]     + cx * Rb[6 + j];
  p[3]  = fx * tb[0] + cx * tb[2];
  for (int j = 0; j < 3; j++) p[4 + j] = fy * Rb[3 + j] + cy * Rb[6 + j];
  p[7]  = fy * tb[1] + cy * tb[2];
  for (int j = 0; j < 3; j++) p[8 + j] = Rb[6 + j];
  p[11] = tb[2];
}

// ============ K1: cam_feat (S,C,H,W) f32 -> camT (S,H,W,C) bf16 ============
__global__ __launch_bounds__(128) void k1_transpose(const float* __restrict__ feat,
                                                    __hip_bfloat16* __restrict__ camT) {
  const int b = blockIdx.x;
  const int wq = b & 3;
  const int sh = b >> 2;
  const int c = threadIdx.x;
  const float* src = feat + ((size_t)(sh / HF) * CC + c) * (HF * WF) + (sh % HF) * WF + wq * 22;
  __hip_bfloat16* dst = camT + ((size_t)sh * WF + wq * 22) * CC + c;
  for (int w = 0; w < 22; w++) dst[w * CC] = __float2bfloat16(src[w]);
}

// ============ K1b: conv_w (co,ci,3,3) f32 -> Wp[d][co*1024+ci] bf16 ============
__global__ __launch_bounds__(256) void k1b_packw(const float* __restrict__ w,
                                                 __hip_bfloat16* __restrict__ wp) {
  const int t = blockIdx.x * 256 + threadIdx.x;
  float v[9];
  #pragma unroll
  for (int d = 0; d < 9; d++) v[d] = w[(size_t)t * 9 + d];
  #pragma unroll
  for (int d = 0; d < 9; d++) wp[(size_t)d * 131072 + t] = __float2bfloat16(v[d]);
}

// ============ K2: project + bilinear + mask-average -> Fpack (halo-padded) ====
// v5: block-uniform per-y camera bitmask (one ballot in wave 0) replaces the
// per-thread 12x Rec-load+zero-check scan; phase 2 iterates only valid recs
// via a uniform ctz loop. Removes ~70% of phase-2 LDS reads + compares.
struct Rec { int off[4]; float w[4]; };

__global__ __launch_bounds__(256) void k2_sample(const __hip_bfloat16* __restrict__ camT,
                                                 const float* __restrict__ P,
                                                 __hip_bfloat16* __restrict__ F) {
  const int bz = blockIdx.x / 130;
  const int bx = blockIdx.x % 130;
  const int t = threadIdx.x;
  const int zi = bz - 1, xi = bx - 1;
  const int c = (t & 63) << 1;      // channel pair base 0,2,..,126
  const int yq = t >> 6;            // y quarter: handles y = yq*2, yq*2+1
  __hip_bfloat16* Fb = F + (size_t)blockIdx.x * 1024;
  if (zi < 0 || zi >= ZD || xi < 0 || xi >= XD) {
    *reinterpret_cast<unsigned*>(Fb + c * 8 + yq * 2) = 0u;
    *reinterpret_cast<unsigned*>(Fb + (c + 1) * 8 + yq * 2) = 0u;
    return;
  }
  __shared__ Rec recs[48];
  __shared__ unsigned ymask[8];     // per-y bitmask of valid cameras
  bool vflag = false;
  if (t < 48) {
    const int y = t / 6, s = t - y * 6;
    const float* pp = P + s * 12;
    const float vx = 100.0f / 128.0f;
    const float xw = xi * vx - 50.0f + vx * 0.5f;
    const float zw = zi * vx - 50.0f + vx * 0.5f;
    const float yw = y * 1.25f - 4.0f + 0.625f;
    const float zc = pp[8] * xw + pp[9] * yw + pp[10] * zw + pp[11];
    const float xp = pp[0] * xw + pp[1] * yw + pp[2] * zw + pp[3];
    const float yp = pp[4] * xw + pp[5] * yw + pp[6] * zw + pp[7];
    const float dep = fmaxf(zc, 1e-4f);
    const float pxf = xp / dep, pyf = yp / dep;
    const bool valid = (pxf > -0.5f && pxf < (float)WF - 0.5f &&
                        pyf > -0.5f && pyf < (float)HF - 0.5f && zc > 0.0f);
    const float px = pxf * ((float)WF / (float)(WF - 1)) - 0.5f;
    const float py = pyf * ((float)HF / (float)(HF - 1)) - 0.5f;
    const float fx0 = floorf(px), fy0 = floorf(py);
    const float ddx = px - fx0, ddy = py - fy0;
    const int x0i = (int)fx0, y0i = (int)fy0;
    const float vf = valid ? 1.0f : 0.0f;
    float ww[4];
    ww[0] = (1.0f - ddx) * (1.0f - ddy) * vf;
    ww[1] = ddx * (1.0f - ddy) * vf;
    ww[2] = (1.0f - ddx) * ddy * vf;
    ww[3] = ddx * ddy * vf;
    const int cxs[4] = {x0i, x0i + 1, x0i, x0i + 1};
    const int cys[4] = {y0i, y0i, y0i + 1, y0i + 1};
    Rec r;
    float wsum = 0.f;
    #pragma unroll
    for (int k = 0; k < 4; k++) {
      const bool inb = ((unsigned)cxs[k] < WF) && ((unsigned)cys[k] < HF);
      const int xc = min(max(cxs[k], 0), WF - 1);
      const int yc = min(max(cys[k], 0), HF - 1);
      r.w[k] = inb ? ww[k] : 0.0f;
      r.off[k] = (s * (HF * WF) + yc * WF + xc) * CC;
      wsum += r.w[k];
    }
    recs[t] = r;
    vflag = wsum > 0.0f;            // non-negative weights: >0 <=> not all zero
  }
  if (t < 64) {                     // wave 0 summarizes validity (uniform exec)
    unsigned long long m = __ballot(vflag);
    if (t < 8) ymask[t] = (unsigned)((m >> (6 * t)) & 63ull);
  }
  __syncthreads();

  float num[2][2] = {{0.f, 0.f}, {0.f, 0.f}};
  int cnt[2] = {0, 0};
  #pragma unroll
  for (int yi = 0; yi < 2; yi++) {
    const int y = yq * 2 + yi;
    unsigned ms = ymask[y];         // block-uniform
    while (ms) {
      const int s = __builtin_ctz(ms);
      ms &= ms - 1;
      const Rec r = recs[y * 6 + s];
      float v0 = 0.f, v1 = 0.f;
      #pragma unroll
      for (int k = 0; k < 4; k++) {
        const ushort2 uv = *reinterpret_cast<const ushort2*>(&camT[r.off[k] + c]);
        v0 += r.w[k] * __bfloat162float(*reinterpret_cast<const __hip_bfloat16*>(&uv.x));
        v1 += r.w[k] * __bfloat162float(*reinterpret_cast<const __hip_bfloat16*>(&uv.y));
      }
      num[yi][0] += v0;
      num[yi][1] += v1;
      cnt[yi]++;
    }
  }
  #pragma unroll
  for (int j = 0; j < 2; j++) {
    __hip_bfloat16 o[2];
    const float inv0 = 1.0f / (1e-6f + (float)cnt[0]);
    const float inv1 = 1.0f / (1e-6f + (float)cnt[1]);
    o[0] = __float2bfloat16(num[0][j] * inv0);
    o[1] = __float2bfloat16(num[1][j] * inv1);
    *reinterpret_cast<unsigned*>(Fb + (c + j) * 8 + yq * 2) =
        *reinterpret_cast<const unsigned*>(o);
  }
}

// ============ K3: implicit-GEMM 3x3 conv, bf16 MFMA ============
// v3 (best measured: 54.6-54.8 us, FROZEN). 128x128 tile, BK=64, split-K=2
// across blocks (ci-halves) AND kk-split inside the block. Per-wave output
// 64x64 (acc 4x4). One 64KB LDS reduction merges kk pairs at the end.
// Ring-4 staging, counted vmcnt(8), no atomics.
__device__ __forceinline__ void load_lds16(const void* g, void* l) {
  __builtin_amdgcn_global_load_lds(
      (const __attribute__((address_space(1))) unsigned int*)g,
      (__attribute__((address_space(3))) unsigned int*)l, 16, 0, 0);
}

#define K3_NT 72   // 9 taps * 8 ci-chunks (ci-half of 512, BK=64)

__global__ __launch_bounds__(512) void k3_gemm(const __hip_bfloat16* __restrict__ F,
                                               const __hip_bfloat16* __restrict__ Wp,
                                               float* __restrict__ out0,
                                               float* __restrict__ out1) {
  // XCD-aware swizzle: 32 consecutive logical blocks per XCD (256 = 8*32).
  const int orig = (blockIdx.x & 7) * 32 + (blockIdx.x >> 3);
  const int z = orig & 127;
  const int h = orig >> 7;          // ci-half: 0 -> ci 0..511, 1 -> 512..1023
  const int ciH = h << 9;
  const int tid = threadIdx.x;
  const int w = tid >> 6;           // wave 0..7
  const int l = tid & 63;
  const int kk = w >> 2;            // in-block K-group (ci sub-chunks)
  const int wq = w & 3;
  const int wm = wq >> 1;           // 0..1  (64 x-rows)
  const int wn = wq & 1;            // 0..1  (64 co)
  __shared__ __hip_bfloat16 lds[4][16384];  // ring: A[128][64] + B[128][64] per stage (32KB)

  f32x4 acc[4][4];
  #pragma unroll
  for (int m = 0; m < 4; m++)
    #pragma unroll
    for (int n = 0; n < 4; n++)
      acc[m][n] = (f32x4){0.f, 0.f, 0.f, 0.f};

  auto stage = [&](int kt) {
    const int buf = kt & 3;
    const int d = kt >> 3;                    // tap 0..8
    const int dz = d / 3, dx = d - dz * 3;
    const int ci0 = ciH + ((kt & 7) << 6);
    const int zbase = (z + dz) * 130 + dx;
    // A: 128 x-rows x 64 ci = 1024 x 16B chunks; chunk n -> (row=n>>3, slot=n&7)
    // content at (row,slot) = ci-chunk (slot ^ (row&7))  [XOR swizzle]
    #pragma unroll
    for (int i = 0; i < 2; i++) {
      const int n = w * 128 + i * 64 + l;
      const int row = n >> 3;
      const int q = (n & 7) ^ (row & 7);
      const __hip_bfloat16* src = F + ((size_t)(zbase + row) << 10) + ci0 + (q << 3);
      load_lds16(src, &lds[buf][(w * 128 + i * 64) * 8]);
    }
    // B: 128 co x 64 ci, same swizzle
    #pragma unroll
    for (int i = 0; i < 2; i++) {
      const int n = w * 128 + i * 64 + l;
      const int co = n >> 3;
      const int q = (n & 7) ^ (co & 7);
      const __hip_bfloat16* src = Wp + ((size_t)d << 17) + ((size_t)co << 10) + ci0 + (q << 3);
      load_lds16(src, &lds[buf][8192 + (w * 128 + i * 64) * 8]);
    }
  };

  auto compute = [&](int kt) {
    const int buf = kt & 3;
    const int r16 = l & 15;
    const int hi = l >> 4;
    const int c = kk * 4 + hi;                // 16B ci-chunk 0..7 (kk-split)
    bf16x8 a[4], b[4];
    #pragma unroll
    for (int m = 0; m < 4; m++) {
      const int r = wm * 64 + m * 16 + r16;
      const int slot = c ^ (r & 7);
      a[m] = *reinterpret_cast<const bf16x8*>(&lds[buf][r * 64 + slot * 8]);
    }
    #pragma unroll
    for (int n = 0; n < 4; n++) {
      const int co = wn * 64 + n * 16 + r16;
      const int slot = c ^ (co & 7);
      b[n] = *reinterpret_cast<const bf16x8*>(&lds[buf][8192 + co * 64 + slot * 8]);
    }
    #pragma unroll
    for (int m = 0; m < 4; m++)
      #pragma unroll
      for (int n = 0; n < 4; n++)
        acc[m][n] = __builtin_amdgcn_mfma_f32_16x16x32_bf16(a[m], b[n], acc[m][n], 0, 0, 0);
  };

  // prologue: 3 stages in flight (12 outstanding loads/wave)
  stage(0); stage(1); stage(2);

  // main loop: wait only for oldest stage (vmcnt 8 = 2 stages still in flight)
  for (int t = 0; t < K3_NT - 2; ++t) {
    asm volatile("s_waitcnt vmcnt(8)" ::: "memory");
    __builtin_amdgcn_s_barrier();
    if (t + 3 < K3_NT) stage(t + 3);
    compute(t);
  }
  asm volatile("s_waitcnt vmcnt(4)" ::: "memory");
  __builtin_amdgcn_s_barrier();
  compute(K3_NT - 2);
  asm volatile("s_waitcnt vmcnt(0)" ::: "memory");
  __builtin_amdgcn_s_barrier();
  compute(K3_NT - 1);

  // ---- merge kk pairs: waves 4-7 dump acc to LDS, waves 0-3 add + store ----
  float* red = reinterpret_cast<float*>(&lds[0][0]);   // 64 KB scratch (bufs 0-1)
  if (kk == 1) {
    float* dst = red + wq * 4096;
    #pragma unroll
    for (int m = 0; m < 4; m++)
      #pragma unroll
      for (int n = 0; n < 4; n++)
        *reinterpret_cast<f32x4*>(&dst[(m * 4 + n) * 256 + l * 4]) = acc[m][n];
  }
  __syncthreads();
  if (kk == 0) {
    const float* srcr = red + wq * 4096;
    float* outP = h ? out1 : out0;
    const int r16 = l & 15;
    const int hi = l >> 4;
    #pragma unroll
    for (int m = 0; m < 4; m++) {
      const int xr = wm * 64 + m * 16 + hi * 4;
      #pragma unroll
      for (int n = 0; n < 4; n++) {
        f32x4 o = *reinterpret_cast<const f32x4*>(&srcr[(m * 4 + n) * 256 + l * 4]);
        f32x4 r = acc[m][n] + o;
        const int co = wn * 64 + n * 16 + r16;
        *reinterpret_cast<f32x4*>(&outP[((size_t)co << 14) + (z << 7) + xr]) = r;
      }
    }
  }
}

// ============ K4: fused split-K reduce + per-channel LN + exact GELU ============
// v2: 1024 threads/block (was 256) -> v[4] instead of v[16]: no VGPR spill
// (old: 64-reg array vs VGPR_Count=60 -> 16MB scratch round-trip), 4x waves.
__device__ __forceinline__ float gelu_exact(float x) {
  return 0.5f * x * (1.0f + erff(x * 0.70710678118654752440f));
}

__global__ __launch_bounds__(1024) void k4_ln(const float* __restrict__ c0,
                                              const float* __restrict__ c1,
                                              float* __restrict__ outp) {
  const int co = blockIdx.x;
  const int t = threadIdx.x;
  const float4* p0 = reinterpret_cast<const float4*>(c0 + ((size_t)co << 14));
  const float4* p1 = reinterpret_cast<const float4*>(c1 + ((size_t)co << 14));
  float4 v[4];
  float s = 0.f, s2 = 0.f;
  #pragma unroll
  for (int i = 0; i < 4; i++) {
    float4 a = p0[t + (i << 10)];
    float4 b = p1[t + (i << 10)];
    float4 r;
    r.x = a.x + b.x; r.y = a.y + b.y; r.z = a.z + b.z; r.w = a.w + b.w;
    v[i] = r;
    s  += r.x + r.y + r.z + r.w;
    s2 += r.x * r.x + r.y * r.y + r.z * r.z + r.w * r.w;
  }
  #pragma unroll
  for (int off = 32; off > 0; off >>= 1) {
    s  += __shfl_down(s, off);
    s2 += __shfl_down(s2, off);
  }
  __shared__ float red[32];
  __shared__ float mb[2];
  const int wv = t >> 6, ln = t & 63;
  if (ln == 0) { red[wv] = s; red[wv + 16] = s2; }
  __syncthreads();
  if (t == 0) {
    float S = 0.f, S2 = 0.f;
    #pragma unroll
    for (int i = 0; i < 16; i++) { S += red[i]; S2 += red[i + 16]; }
    float mu = S * (1.0f / 16384.0f);
    float var = S2 * (1.0f / 16384.0f) - mu * mu;
    mb[0] = mu;
    mb[1] = 1.0f / sqrtf(var + 1e-5f);
  }
  __syncthreads();
  const float mu = mb[0], inv = mb[1];
  float4* op = reinterpret_cast<float4*>(outp + ((size_t)co << 14));
  #pragma unroll
  for (int i = 0; i < 4; i++) {
    float4 x = v[i];
    float4 r;
    r.x = gelu_exact((x.x - mu) * inv);
    r.y = gelu_exact((x.y - mu) * inv);
    r.z = gelu_exact((x.z - mu) * inv);
    r.w = gelu_exact((x.w - mu) * inv);
    op[t + (i << 10)] = r;
  }
}

extern "C" void kernel_launch(void* const* d_in, const int* in_sizes, int n_in,
                              void* d_out, int out_size, void* d_ws, size_t ws_size,
                              hipStream_t stream) {
  const float* cam_feat = (const float*)d_in[0];
  const float* cam2ego  = (const float*)d_in[1];
  const float* intr     = (const float*)d_in[2];
  const float* conv_w   = (const float*)d_in[3];
  float* out = (float*)d_out;
  char* ws = (char*)d_ws;

  float*          P     = (float*)(ws + OFF_P);
  __hip_bfloat16* Wp    = (__hip_bfloat16*)(ws + OFF_W);
  __hip_bfloat16* camT  = (__hip_bfloat16*)(ws + OFF_CAMT);
  __hip_bfloat16* F     = (__hip_bfloat16*)(ws + OFF_F);
  float*          conv0 = (float*)(ws + OFF_CONV);
  float*          conv1 = (float*)(ws + OFF_CAMT);  // camT slot is dead after k2

  hipLaunchKernelGGL(k0_mats, dim3(1), dim3(64), 0, stream, cam2ego, intr, P);
  hipLaunchKernelGGL(k1_transpose, dim3(NCAM * HF * 4), dim3(128), 0, stream, cam_feat, camT);
  hipLaunchKernelGGL(k1b_packw, dim3(512), dim3(256), 0, stream, conv_w, Wp);
  hipLaunchKernelGGL(k2_sample, dim3(130 * 130), dim3(256), 0, stream, camT, P, F);
  hipLaunchKernelGGL(k3_gemm, dim3(256), dim3(512), 0, stream, F, Wp, conv0, conv1);
  hipLaunchKernelGGL(k4_ln, dim3(128), dim3(1024), 0, stream, conv0, conv1, out);
}